// Round 5
// baseline (93.256 us; speedup 1.0000x reference)
//
#include <hip/hip_runtime.h>
#include <math.h>

#define NROWS 4096
#define DDIM  256
#define BM 128
#define BN 128
#define LOG2E2 2.8853900817779268f   // 2*log2(e): exp(2S) = exp2(LOG2E2 * S)

typedef __attribute__((ext_vector_type(8))) short short8;  // 8 bf16 (4 VGPRs)
typedef __attribute__((ext_vector_type(4))) float f32x4;   // MFMA 16x16 C/D

__device__ __forceinline__ unsigned short f2bf(float f) {  // RNE float->bf16
    unsigned int u = __float_as_uint(f);
    u += 0x7fffu + ((u >> 16) & 1u);
    return (unsigned short)(u >> 16);
}

__device__ __forceinline__ float exp2_fast(float x) {
#if __has_builtin(__builtin_amdgcn_exp2f)
    return __builtin_amdgcn_exp2f(x);
#else
    return exp2f(x);
#endif
}

// global -> LDS direct DMA, 16B per lane. LDS dest is wave-uniform base
// (lane offset implicit +lane*16); global src is per-lane (pre-swizzled).
#define GLOAD_LDS16(gsrc, ldst)                                          \
    __builtin_amdgcn_global_load_lds(                                    \
        (__attribute__((address_space(1))) void*)(gsrc),                 \
        (__attribute__((address_space(3))) void*)(ldst), 16, 0, 0)

// ---------------- Kernel 1: L2-normalize rows + positive dots ----------------
// 1 wave per row. pos computed in fp32 (exact); bf16 copies written for MFMA.
// A-side (zi) pre-scaled by 2*log2(e) so the GEMM accumulator is exp2-ready.
// Also zeroes the rowsum/colsum accumulators (8 floats per block) so no
// separate memset dispatch is needed.
__global__ __launch_bounds__(256) void normalize_kernel(
    const float* __restrict__ emb_i, const float* __restrict__ emb_j,
    unsigned short* __restrict__ zi, unsigned short* __restrict__ zj,
    float* __restrict__ pos, float* __restrict__ sums /*rowsum..colsum, 2N*/)
{
    // Zero 8192 accumulator floats across 1024 blocks (8 each).
    if (threadIdx.x < 8) sums[blockIdx.x * 8 + threadIdx.x] = 0.0f;

    const int wave = threadIdx.x >> 6;
    const int lane = threadIdx.x & 63;
    const int row  = blockIdx.x * 4 + wave;

    const float4 vi = *((const float4*)(emb_i + (size_t)row * DDIM) + lane);
    const float4 vj = *((const float4*)(emb_j + (size_t)row * DDIM) + lane);

    float ssi = vi.x*vi.x + vi.y*vi.y + vi.z*vi.z + vi.w*vi.w;
    float ssj = vj.x*vj.x + vj.y*vj.y + vj.z*vj.z + vj.w*vj.w;
    #pragma unroll
    for (int m = 1; m < 64; m <<= 1) {
        ssi += __shfl_xor(ssi, m);
        ssj += __shfl_xor(ssj, m);
    }
    const float ri = 1.0f / fmaxf(sqrtf(ssi), 1e-12f);
    const float rj = 1.0f / fmaxf(sqrtf(ssj), 1e-12f);

    const float zix = vi.x*ri, ziy = vi.y*ri, ziz = vi.z*ri, ziw = vi.w*ri;
    const float zjx = vj.x*rj, zjy = vj.y*rj, zjz = vj.z*rj, zjw = vj.w*rj;

    float p = zix*zjx + ziy*zjy + ziz*zjz + ziw*zjw;
    #pragma unroll
    for (int m = 1; m < 64; m <<= 1) p += __shfl_xor(p, m);
    if (lane == 0) pos[row] = p;

    ushort4 oi = { f2bf(zix*LOG2E2), f2bf(ziy*LOG2E2), f2bf(ziz*LOG2E2), f2bf(ziw*LOG2E2) };
    ushort4 oj = { f2bf(zjx), f2bf(zjy), f2bf(zjz), f2bf(zjw) };
    *((ushort4*)(zi + (size_t)row * DDIM) + lane) = oi;
    *((ushort4*)(zj + (size_t)row * DDIM) + lane) = oj;
}

// ---------- Kernel 2: bf16 MFMA S-tile + exp2 + row/col partial sums ----------
// 128x128 tile, WHOLE K=256 staged in one shot (A,B panels 64KB each -> 128KB
// LDS, 1 block/CU). 4 waves (2x2), each wave 64x64 = 4x4 frags x 8 k-frags of
// 16x16x32 MFMA. Exactly TWO barriers per block: after the single stage, and
// none in the MFMA loop. XOR-swizzle (byte ^= (row&7)<<4) applied on the
// pre-swizzled global SOURCE and on the ds_read (both-sides rule #21).
__global__ __launch_bounds__(256) void gemm_fused_kernel(
    const unsigned short* __restrict__ zi, const unsigned short* __restrict__ zj,
    float* __restrict__ rowsum, float* __restrict__ colsum)
{
    __shared__ unsigned short As[BM * DDIM];   // 64 KiB
    __shared__ unsigned short Bs[BN * DDIM];   // 64 KiB

    const int tid  = threadIdx.x;
    const int lane = tid & 63;
    const int wave = tid >> 6;     // 0..3
    const int g    = lane >> 4;    // k-group 0..3
    const int fr   = lane & 15;    // fragment row 0..15
    const int wr   = wave >> 1;    // wave row 0..1
    const int wc   = wave & 1;     // wave col 0..1
    const int bm   = blockIdx.x * BM;
    const int bn   = blockIdx.y * BN;

    f32x4 acc[4][4] = {};          // all indices compile-time (rule #20)

    // Stage both full-K panels: per array 128 rows x 32 16B-slots = 4096 slots,
    // 16 rounds x 256 threads. Linear slot L -> row = L>>5, slot = L&31;
    // source col slot = slot ^ (row&7) (same involution as the read side).
    #pragma unroll
    for (int it = 0; it < 16; ++it) {
        const int L    = it * 256 + tid;
        const int row  = L >> 5;
        const int sl   = L & 31;
        const int soff = ((sl ^ (row & 7)) << 3);        // ushort offset in row
        const int lb   = (it * 256 + wave * 64) << 3;    // wave-uniform, ushorts
        GLOAD_LDS16(zi + (size_t)(bm + row) * DDIM + soff, As + lb);
        GLOAD_LDS16(zj + (size_t)(bn + row) * DDIM + soff, Bs + lb);
    }
    __syncthreads();   // single barrier: drains all 32 outstanding loads

    #pragma unroll
    for (int kk = 0; kk < 8; ++kk) {
        const int cs = kk * 4 + g;                        // k-slot 0..31
        short8 a[4], b[4];
        #pragma unroll
        for (int mi = 0; mi < 4; ++mi) {
            const int row = wr * 64 + mi * 16 + fr;       // row&7 == fr&7
            a[mi] = *(const short8*)&As[row * DDIM + ((cs ^ (fr & 7)) << 3)];
        }
        #pragma unroll
        for (int ni = 0; ni < 4; ++ni) {
            const int row = wc * 64 + ni * 16 + fr;
            b[ni] = *(const short8*)&Bs[row * DDIM + ((cs ^ (fr & 7)) << 3)];
        }
        #pragma unroll
        for (int mi = 0; mi < 4; ++mi)
            #pragma unroll
            for (int ni = 0; ni < 4; ++ni)
                acc[mi][ni] = __builtin_amdgcn_mfma_f32_16x16x32_bf16(
                    a[mi], b[ni], acc[mi][ni], 0, 0, 0);
    }

    // Epilogue. acc[mi][ni][j] = LOG2E2 * S at row bm+wr*64+mi*16+g*4+j,
    // col bn+wc*64+ni*16+fr (C/D layout verified absmax=0 in R3).
    float rp[4][4];
    float cp[4] = {0.f, 0.f, 0.f, 0.f};
    #pragma unroll
    for (int mi = 0; mi < 4; ++mi)
        #pragma unroll
        for (int j = 0; j < 4; ++j) rp[mi][j] = 0.f;

    #pragma unroll
    for (int mi = 0; mi < 4; ++mi)
        #pragma unroll
        for (int ni = 0; ni < 4; ++ni)
            #pragma unroll
            for (int j = 0; j < 4; ++j) {
                const float e = exp2_fast(acc[mi][ni][j]);
                rp[mi][j] += e;
                cp[ni]    += e;
            }

    // Row sums: reduce over cols = lane bits 0..3.
    #pragma unroll
    for (int mi = 0; mi < 4; ++mi)
        #pragma unroll
        for (int j = 0; j < 4; ++j) {
            float v = rp[mi][j];
            v += __shfl_xor(v, 1); v += __shfl_xor(v, 2);
            v += __shfl_xor(v, 4); v += __shfl_xor(v, 8);
            if (fr == 0)
                atomicAdd(&rowsum[bm + wr * 64 + mi * 16 + g * 4 + j], v);
        }

    // Col sums: reduce over row-groups = lane bits 4,5.
    #pragma unroll
    for (int ni = 0; ni < 4; ++ni) {
        float v = cp[ni];
        v += __shfl_xor(v, 16); v += __shfl_xor(v, 32);
        if (g == 0)
            atomicAdd(&colsum[bn + wc * 64 + ni * 16 + fr], v);
    }
}

// ---------------- Kernel 3: final loss reduction ----------------
__global__ __launch_bounds__(512) void finalize_kernel(
    const float* __restrict__ pos, const float* __restrict__ rowsum,
    const float* __restrict__ colsum, float* __restrict__ out)
{
    float s = 0.0f;
    for (int r = threadIdx.x; r < NROWS; r += 512) {
        // log(0.5*a) + log(0.5*b) = log(0.25*a*b)
        s += -4.0f * pos[r] + logf(0.25f * rowsum[r] * colsum[r]);
    }
    __shared__ float part[8];
    #pragma unroll
    for (int m = 1; m < 64; m <<= 1) s += __shfl_xor(s, m);
    if ((threadIdx.x & 63) == 0) part[threadIdx.x >> 6] = s;
    __syncthreads();
    if (threadIdx.x == 0) {
        float t = 0.f;
        #pragma unroll
        for (int w = 0; w < 8; ++w) t += part[w];
        out[0] = t / (2.0f * NROWS);
    }
}

extern "C" void kernel_launch(void* const* d_in, const int* in_sizes, int n_in,
                              void* d_out, int out_size, void* d_ws, size_t ws_size,
                              hipStream_t stream)
{
    const float* emb_i = (const float*)d_in[0];
    const float* emb_j = (const float*)d_in[1];

    unsigned short* zi = (unsigned short*)d_ws;               // N*D bf16 (scaled)
    unsigned short* zj = zi + (size_t)NROWS * DDIM;           // N*D bf16
    float* pos    = (float*)(zj + (size_t)NROWS * DDIM);      // N
    float* rowsum = pos + NROWS;                              // N
    float* colsum = rowsum + NROWS;                           // N (contiguous with rowsum)

    normalize_kernel<<<NROWS / 4, 256, 0, stream>>>(emb_i, emb_j, zi, zj, pos, rowsum);

    dim3 grid(NROWS / BM, NROWS / BN);   // 32 x 32 = 1024 blocks
    gemm_fused_kernel<<<grid, 256, 0, stream>>>(zi, zj, rowsum, colsum);

    finalize_kernel<<<1, 512, 0, stream>>>(pos, rowsum, colsum, (float*)d_out);
}

// Round 6
// 77.347 us; speedup vs baseline: 1.2057x; 1.2057x over previous
//
#include <hip/hip_runtime.h>
#include <math.h>

#define NROWS 4096
#define DDIM  256
#define BM 128
#define BN 256
#define BK 64
#define LOG2E2 2.8853900817779268f   // 2*log2(e): exp(2S) = exp2(LOG2E2 * S)

typedef __attribute__((ext_vector_type(8))) short short8;  // 8 bf16 (4 VGPRs)
typedef __attribute__((ext_vector_type(4))) float f32x4;   // MFMA 16x16 C/D

__device__ __forceinline__ unsigned short f2bf(float f) {  // RNE float->bf16
    unsigned int u = __float_as_uint(f);
    u += 0x7fffu + ((u >> 16) & 1u);
    return (unsigned short)(u >> 16);
}

__device__ __forceinline__ float exp2_fast(float x) {
#if __has_builtin(__builtin_amdgcn_exp2f)
    return __builtin_amdgcn_exp2f(x);
#else
    return exp2f(x);
#endif
}

// global -> LDS direct DMA, 16B per lane. LDS dest is wave-uniform base
// (lane offset implicit +lane*16); global src is per-lane (pre-swizzled).
#define GLOAD_LDS16(gsrc, ldst)                                          \
    __builtin_amdgcn_global_load_lds(                                    \
        (__attribute__((address_space(1))) void*)(gsrc),                 \
        (__attribute__((address_space(3))) void*)(ldst), 16, 0, 0)

// ---------------- Kernel 1: L2-normalize rows + positive dots ----------------
// 1 wave per row. pos computed in fp32 (exact); bf16 copies written for MFMA.
// A-side (zi) pre-scaled by 2*log2(e) so the GEMM accumulator is exp2-ready.
// Also zeroes the rowsum/colsum accumulators (8 floats per block).
__global__ __launch_bounds__(256) void normalize_kernel(
    const float* __restrict__ emb_i, const float* __restrict__ emb_j,
    unsigned short* __restrict__ zi, unsigned short* __restrict__ zj,
    float* __restrict__ pos, float* __restrict__ sums /*rowsum..colsum, 2N*/)
{
    if (threadIdx.x < 8) sums[blockIdx.x * 8 + threadIdx.x] = 0.0f;

    const int wave = threadIdx.x >> 6;
    const int lane = threadIdx.x & 63;
    const int row  = blockIdx.x * 4 + wave;

    const float4 vi = *((const float4*)(emb_i + (size_t)row * DDIM) + lane);
    const float4 vj = *((const float4*)(emb_j + (size_t)row * DDIM) + lane);

    float ssi = vi.x*vi.x + vi.y*vi.y + vi.z*vi.z + vi.w*vi.w;
    float ssj = vj.x*vj.x + vj.y*vj.y + vj.z*vj.z + vj.w*vj.w;
    #pragma unroll
    for (int m = 1; m < 64; m <<= 1) {
        ssi += __shfl_xor(ssi, m);
        ssj += __shfl_xor(ssj, m);
    }
    const float ri = 1.0f / fmaxf(sqrtf(ssi), 1e-12f);
    const float rj = 1.0f / fmaxf(sqrtf(ssj), 1e-12f);

    const float zix = vi.x*ri, ziy = vi.y*ri, ziz = vi.z*ri, ziw = vi.w*ri;
    const float zjx = vj.x*rj, zjy = vj.y*rj, zjz = vj.z*rj, zjw = vj.w*rj;

    float p = zix*zjx + ziy*zjy + ziz*zjz + ziw*zjw;
    #pragma unroll
    for (int m = 1; m < 64; m <<= 1) p += __shfl_xor(p, m);
    if (lane == 0) pos[row] = p;

    ushort4 oi = { f2bf(zix*LOG2E2), f2bf(ziy*LOG2E2), f2bf(ziz*LOG2E2), f2bf(ziw*LOG2E2) };
    ushort4 oj = { f2bf(zjx), f2bf(zjy), f2bf(zjz), f2bf(zjw) };
    *((ushort4*)(zi + (size_t)row * DDIM) + lane) = oi;
    *((ushort4*)(zj + (size_t)row * DDIM) + lane) = oj;
}

// ---------- Kernel 2: bf16 MFMA S-tile + exp2 + row/col partial sums ----------
// 128x256 tile per block, 4 waves (2x2), each wave 64x128 out = 4x8 frags of
// 16x16x32 MFMA. BK=64 single-buffered LDS: As 16KB + Bs 32KB = 48KB ->
// 2 blocks/CU; grid 32x16 = 512 blocks = ALL co-resident (no serial rounds —
// each block's barrier drains overlap the sibling block's compute).
// XOR-swizzle (byte ^= (row&7)<<4) on pre-swizzled SOURCE and ds_read (#21).
__global__ __launch_bounds__(256, 2) void gemm_fused_kernel(
    const unsigned short* __restrict__ zi, const unsigned short* __restrict__ zj,
    float* __restrict__ rowsum, float* __restrict__ colsum)
{
    __shared__ unsigned short As[BM * BK];   // 16 KiB
    __shared__ unsigned short Bs[BN * BK];   // 32 KiB

    const int tid  = threadIdx.x;
    const int lane = tid & 63;
    const int wave = tid >> 6;     // 0..3
    const int g    = lane >> 4;    // k-group 0..3
    const int fr   = lane & 15;    // fragment row 0..15
    const int wr   = wave >> 1;    // wave row 0..1 (64-row halves)
    const int wc   = wave & 1;     // wave col 0..1 (128-col halves)
    const int bm   = blockIdx.x * BM;
    const int bn   = blockIdx.y * BN;

    f32x4 acc[4][8] = {};          // 128 VGPR; all indices compile-time

    // Staging: linear 16B slot L -> row = L>>3, slot = L&7 (BK=64 = 8 slots),
    // source col slot = slot ^ (row&7)  (same involution as the read side).
    const int srow = tid >> 3;                           // 0..31
    const int soff = (((tid & 7) ^ (srow & 7)) << 3);    // ushort offset in row

    for (int k0 = 0; k0 < DDIM; k0 += BK) {
        // A: 128 rows x 8 slots = 1024 slots = 4 rounds.
        #pragma unroll
        for (int it = 0; it < 4; ++it) {
            const int row = it * 32 + srow;
            const int lb  = (it * 256 + wave * 64) << 3;   // wave-uniform, ushorts
            GLOAD_LDS16(zi + (size_t)(bm + row) * DDIM + k0 + soff, As + lb);
        }
        // B: 256 rows x 8 slots = 2048 slots = 8 rounds.
        #pragma unroll
        for (int it = 0; it < 8; ++it) {
            const int row = it * 32 + srow;
            const int lb  = (it * 256 + wave * 64) << 3;
            GLOAD_LDS16(zj + (size_t)(bn + row) * DDIM + k0 + soff, Bs + lb);
        }
        __syncthreads();   // drain staging (compiler emits vmcnt(0) before barrier)

        #pragma unroll
        for (int kk = 0; kk < 2; ++kk) {
            const int coff = (((kk * 4 + g) ^ (fr & 7)) << 3);
            short8 a[4], b[8];
            #pragma unroll
            for (int mi = 0; mi < 4; ++mi)
                a[mi] = *(const short8*)&As[(wr * 64 + mi * 16 + fr) * BK + coff];
            #pragma unroll
            for (int ni = 0; ni < 8; ++ni)
                b[ni] = *(const short8*)&Bs[(wc * 128 + ni * 16 + fr) * BK + coff];
            #pragma unroll
            for (int mi = 0; mi < 4; ++mi)
                #pragma unroll
                for (int ni = 0; ni < 8; ++ni)
                    acc[mi][ni] = __builtin_amdgcn_mfma_f32_16x16x32_bf16(
                        a[mi], b[ni], acc[mi][ni], 0, 0, 0);
        }
        __syncthreads();   // WAR: single-buffer reuse next K-iter
    }

    // Epilogue. acc[mi][ni][j] = LOG2E2 * S at row bm+wr*64+mi*16+g*4+j,
    // col bn+wc*128+ni*16+fr (C/D layout verified absmax=0 in R3/R4/R5).
    float rp[4][4];
    float cp[8] = {0.f,0.f,0.f,0.f,0.f,0.f,0.f,0.f};
    #pragma unroll
    for (int mi = 0; mi < 4; ++mi)
        #pragma unroll
        for (int j = 0; j < 4; ++j) rp[mi][j] = 0.f;

    #pragma unroll
    for (int mi = 0; mi < 4; ++mi)
        #pragma unroll
        for (int ni = 0; ni < 8; ++ni)
            #pragma unroll
            for (int j = 0; j < 4; ++j) {
                const float e = exp2_fast(acc[mi][ni][j]);
                rp[mi][j] += e;
                cp[ni]    += e;
            }

    // Row sums: reduce over cols = lane bits 0..3.
    #pragma unroll
    for (int mi = 0; mi < 4; ++mi)
        #pragma unroll
        for (int j = 0; j < 4; ++j) {
            float v = rp[mi][j];
            v += __shfl_xor(v, 1); v += __shfl_xor(v, 2);
            v += __shfl_xor(v, 4); v += __shfl_xor(v, 8);
            if (fr == 0)
                atomicAdd(&rowsum[bm + wr * 64 + mi * 16 + g * 4 + j], v);
        }

    // Col sums: reduce over row-groups = lane bits 4,5.
    #pragma unroll
    for (int ni = 0; ni < 8; ++ni) {
        float v = cp[ni];
        v += __shfl_xor(v, 16); v += __shfl_xor(v, 32);
        if (g == 0)
            atomicAdd(&colsum[bn + wc * 128 + ni * 16 + fr], v);
    }
}

// ---------------- Kernel 3: final loss reduction ----------------
__global__ __launch_bounds__(512) void finalize_kernel(
    const float* __restrict__ pos, const float* __restrict__ rowsum,
    const float* __restrict__ colsum, float* __restrict__ out)
{
    float s = 0.0f;
    for (int r = threadIdx.x; r < NROWS; r += 512) {
        // log(0.5*a) + log(0.5*b) = log(0.25*a*b)
        s += -4.0f * pos[r] + logf(0.25f * rowsum[r] * colsum[r]);
    }
    __shared__ float part[8];
    #pragma unroll
    for (int m = 1; m < 64; m <<= 1) s += __shfl_xor(s, m);
    if ((threadIdx.x & 63) == 0) part[threadIdx.x >> 6] = s;
    __syncthreads();
    if (threadIdx.x == 0) {
        float t = 0.f;
        #pragma unroll
        for (int w = 0; w < 8; ++w) t += part[w];
        out[0] = t / (2.0f * NROWS);
    }
}

extern "C" void kernel_launch(void* const* d_in, const int* in_sizes, int n_in,
                              void* d_out, int out_size, void* d_ws, size_t ws_size,
                              hipStream_t stream)
{
    const float* emb_i = (const float*)d_in[0];
    const float* emb_j = (const float*)d_in[1];

    unsigned short* zi = (unsigned short*)d_ws;               // N*D bf16 (scaled)
    unsigned short* zj = zi + (size_t)NROWS * DDIM;           // N*D bf16
    float* pos    = (float*)(zj + (size_t)NROWS * DDIM);      // N
    float* rowsum = pos + NROWS;                              // N
    float* colsum = rowsum + NROWS;                           // N (contiguous)

    normalize_kernel<<<NROWS / 4, 256, 0, stream>>>(emb_i, emb_j, zi, zj, pos, rowsum);

    dim3 grid(NROWS / BM, NROWS / BN);   // 32 x 16 = 512 blocks, 2/CU, 1 round
    gemm_fused_kernel<<<grid, 256, 0, stream>>>(zi, zj, rowsum, colsum);

    finalize_kernel<<<1, 512, 0, stream>>>(pos, rowsum, colsum, (float*)d_out);
}